// Round 12
// baseline (117.751 us; speedup 1.0000x reference)
//
#include <hip/hip_runtime.h>

#define Nn 8
#define Cc 4
#define Hh 256
#define Ww 256

typedef unsigned short u16;
typedef u16 u16x4 __attribute__((ext_vector_type(4)));
typedef unsigned long long u64;

// Workspace layout (bytes): partials only
#define OFF_PART 0

// ---------------------------------------------------------------------------
// Merged kernel (R11 body + npass amplification for self-measurement).
// npass=16, scale=1/16 -> bitwise-identical result; marginal pass cost =
// warm steady-state cost; amplified duration makes THIS kernel visible in
// rocprof top-5 with its own counters. Barriers: sync-A (post-mask) and
// sync-B (post-g2) gate all cross-pass LDS hazards (phase-4 reads of pass n
// finish before any wave reaches sync-A of pass n+1).
// ---------------------------------------------------------------------------
__global__ __launch_bounds__(1024) void merged_kernel(
    const int* __restrict__ tgt, const float* __restrict__ in,
    float* __restrict__ partials, int npass, float scale) {
  __shared__ u64 smp[32][4][6];   // [row][class][guard,w0..w3,guard] = 6 KB
  __shared__ u16x4 s2[32][64];    // sat g^2, row r <-> k = i0-8+r   = 16 KB
  __shared__ float s_w[16];
  const int bid = blockIdx.x;     // n*64 + it*4 + jt  (8*16*4 = 512)
  const int n = bid >> 6;
  const int it = (bid >> 2) & 15;
  const int jt = bid & 3;
  const int i0 = it * 16, j0 = jt * 64;
  const int tid = threadIdx.x;
  const int lane = tid & 63;
  const int w = tid >> 6;         // wave 0..15; pixel row i = i0 + w
  const int jj = lane;
  const int j = j0 + jj;
  const int i = i0 + w;

  // ---- 1. logit loads (registers, reused across passes) ----
  const long cs = (long)Hh * Ww;
  const float* lp = in + ((long)(n * Cc) * Hh + i) * Ww + j;
  const float x0 = lp[0];
  const float x1 = lp[cs];
  const float x2 = lp[2 * cs];
  const float x3 = lp[3 * cs];

  // ---- guards (idx 0 and 5), once: passes only write words 1..4 ----
  if (tid < 256) {
    const int r = tid >> 3, c = (tid >> 1) & 3, g01 = (tid & 1) * 5;
    smp[r][c][g01] = 0ull;
  }

  float contrib = 0.0f;
  for (int pass = 0; pass < npass; ++pass) {
    // ---- 2. mask build: wave w -> rows 2w, 2w+1 ----
#pragma unroll
    for (int rr = 0; rr < 2; ++rr) {
      const int r = 2 * w + rr;
      const int k = i0 - 8 + r;
      if (k >= 0 && k < Hh) {     // wave-uniform
        const int rowOff = (n * Hh + k) * Ww;
        const int t0 = tgt[rowOff + lane];
        const int t1 = tgt[rowOff + lane + 64];
        const int t2 = tgt[rowOff + lane + 128];
        const int t3 = tgt[rowOff + lane + 192];
#pragma unroll
        for (int c = 0; c < Cc; ++c) {
          const u64 m0 = __ballot(t0 == c);
          const u64 m1 = __ballot(t1 == c);
          const u64 m2 = __ballot(t2 == c);
          const u64 m3 = __ballot(t3 == c);
          if (lane == 0) {
            smp[r][c][1] = m0; smp[r][c][2] = m1;
            smp[r][c][3] = m2; smp[r][c][4] = m3;
          }
        }
      }
    }
    __syncthreads();  // sync A: smp ready; also orders vs prev-pass phase 4

    // ---- 3. g^2 (clamped at 10): thread (w, jj) handles rows 2w, 2w+1 ----
    const u16 SENT = 0xFE00;      // 65024; +dd(<=64) < 65536, no wrap
#pragma unroll
    for (int rr = 0; rr < 2; ++rr) {
      const int r = 2 * w + rr;
      const int k = i0 - 8 + r;
      u16x4 sq = {SENT, SENT, SENT, SENT};
      if (k >= 0 && k < Hh) {     // wave-uniform
        const int S = j + 32;     // padded bitspace: orig bit x at 64+x
        const int word = S >> 6;  // 0..4
        const int sh = S & 63;
        u16 dv[4];
#pragma unroll
        for (int c = 0; c < Cc; ++c) {
          const u64* M = smp[r][c];
          const u64 lo = M[word];
          const u64 hi = M[word + 1];
          const u64 win = sh ? ((lo >> sh) | (hi << (64 - sh))) : lo;
          const u64 ml = win & 0x1FFFFFFFFull;   // bits [j-32, j]
          const u64 mr = win >> 32;              // bits [j, j+31]
          const int dl = ml ? (__builtin_clzll(ml) - 31) : 512;
          const int dr = mr ? (int)__builtin_ctzll(mr) : 512;
          const int dd = min(min(dl, dr), 10);   // clamp (exactness: see R11)
          dv[c] = (u16)(dd * dd);
        }
        sq.x = dv[0]; sq.y = dv[1]; sq.z = dv[2]; sq.w = dv[3];
      }
      s2[r][jj] = sq;
    }
    __syncthreads();  // sync B: s2 ready

    // ---- 4. 17-tap column window, 1 px/thread: rows w .. w+16 ----
    u16x4 acc = {0xFFFF, 0xFFFF, 0xFFFF, 0xFFFF};
#pragma unroll
    for (int kq = 0; kq <= 16; ++kq) {
      const int dd = (8 - kq) * (8 - kq);       // compile-time constant
      const u16x4 ddv = {(u16)dd, (u16)dd, (u16)dd, (u16)dd};
      const u16x4 t = s2[w + kq][jj] + ddv;     // b64 read + 2x pk_add
      acc = __builtin_elementwise_min(acc, t);  // 2x pk_min
    }
    int d0 = acc.x, d1 = acc.y, d2 = acc.z, d3 = acc.w;

    // ---- 5. exactness check; rare EXACT brute-force fallback ----
    if (max(max(d0, d1), max(d2, d3)) > 81) {   // P ~ 1e-26, exact if taken
      d0 = 0x7fffffff; d1 = 0x7fffffff; d2 = 0x7fffffff; d3 = 0x7fffffff;
      const int* tp = tgt + n * (Hh * Ww);
      for (int p = 0; p < Hh * Ww; ++p) {
        const int t = tp[p];
        const int dy = i - (p >> 8);
        const int dx = j - (p & 255);
        const int dd2 = dy * dy + dx * dx;
        d0 = (t == 0) ? min(d0, dd2) : d0;
        d1 = (t == 1) ? min(d1, dd2) : d1;
        d2 = (t == 2) ? min(d2, dd2) : d2;
        d3 = (t == 3) ? min(d3, dd2) : d3;
      }
    }

    // ---- 6. softmax + loss ----
    const float f0 = (float)d0, f1 = (float)d1;  // exact: < 2^24
    const float f2 = (float)d2, f3 = (float)d3;
    const float mx = fmaxf(fmaxf(x0, x1), fmaxf(x2, x3));
    const float e0 = __expf(x0 - mx), e1 = __expf(x1 - mx);
    const float e2 = __expf(x2 - mx), e3 = __expf(x3 - mx);
    const float rs = 1.0f / (e0 + e1 + e2 + e3);
    const float p0 = e0 * rs, p1 = e1 * rs, p2 = e2 * rs, p3 = e3 * rs;
    // own-class d is exactly 0; exclude it for dbar
    const int q0 = (d0 == 0) ? 0x7fffffff : d0;
    const int q1 = (d1 == 0) ? 0x7fffffff : d1;
    const int q2 = (d2 == 0) ? 0x7fffffff : d2;
    const int q3 = (d3 == 0) ? 0x7fffffff : d3;
    const float dbar = (float)min(min(q0, q1), min(q2, q3));
    const float pt = (d0 == 0) ? p0 : (d1 == 0) ? p1 : (d2 == 0) ? p2 : p3;
    contrib += pt * sqrtf(dbar) -
               (p0 * sqrtf(f0) + p1 * sqrtf(f1) +
                p2 * sqrtf(f2) + p3 * sqrtf(f3));
  }

  // ---- block reduction (deterministic fixed order) ----
#pragma unroll
  for (int off = 32; off > 0; off >>= 1) contrib += __shfl_down(contrib, off);
  if (lane == 0) s_w[w] = contrib;
  __syncthreads();
  if (tid == 0) {
    float v = 0.0f;
#pragma unroll
    for (int q = 0; q < 16; ++q) v += s_w[q];
    partials[bid] = v * scale;    // plain store (no fence/ticket: R7 lesson)
  }
}

// ---------------------------------------------------------------------------
// Finalize: deterministic reduction of 512 partials + scaling
// ---------------------------------------------------------------------------
__global__ __launch_bounds__(256) void finalize_kernel(
    const float* __restrict__ partials, float* __restrict__ out) {
  __shared__ float s_red[256];
  const int tid = threadIdx.x;
  const float v0 = partials[tid];
  const float v1 = partials[tid + 256];
  s_red[tid] = v0 + v1;
  __syncthreads();
  for (int st = 128; st > 0; st >>= 1) {
    if (tid < st) s_red[tid] += s_red[tid + st];
    __syncthreads();
  }
  if (tid == 0)
    out[0] = s_red[0] / (float)(Cc * Nn) / (65536.0f + 1e-6f);
}

extern "C" void kernel_launch(void* const* d_in, const int* in_sizes, int n_in,
                              void* d_out, int out_size, void* d_ws, size_t ws_size,
                              hipStream_t stream) {
  const float* input = (const float*)d_in[0];   // [8,4,256,256] fp32 logits
  const int* target = (const int*)d_in[1];      // [8,256,256] int32
  float* out = (float*)d_out;                   // scalar fp32
  float* partials = (float*)((char*)d_ws + OFF_PART);

  merged_kernel<<<dim3(512), dim3(1024), 0, stream>>>(target, input, partials,
                                                      16, 0.0625f);
  finalize_kernel<<<dim3(1), dim3(256), 0, stream>>>(partials, out);
}

// Round 13
// 16.343 us; speedup vs baseline: 7.2050x; 7.2050x over previous
//
#include <hip/hip_runtime.h>

#define Nn 8
#define Cc 4
#define Hh 256
#define Ww 256

typedef unsigned short u16;
typedef u16 u16x4 __attribute__((ext_vector_type(4)));
typedef unsigned long long u64;

// Workspace layout (bytes): partials only
#define OFF_PART 0

// ---------------------------------------------------------------------------
// Merged kernel, barrier-minimal: block = 1024 thr (16 waves), 16i x 64j tile.
// Phases 2+3 are WAVE-LOCAL: wave w ballot-builds row masks for rows 2w,2w+1
// (SGPRs), picks the 3 relevant 64-bit words by uniform select (window of 64
// consecutive j always splits at lane 32 since j0 % 64 == 0), funnel+clz/ctz
// -> clamped g^2 -> s2. No mask LDS, no guards, ONE barrier before the taps.
// Window math (verified): for pixel j = 64*jt + lane, bits [j-32, j+31] of
// the 256-bit row mask live in words (jt-1, jt, jt+1) (0-padded at edges);
// lo = word of bit j-32 = (lane<32 ? W[jt-1] : W[jt]), sh = (lane+32)&63,
// win = sh ? (lo>>sh)|(hi<<(64-sh)) : lo;  ml = win & (2^33-1) covers
// [j-32, j] (bit 32 = col j), mr = win>>32 covers [j, j+31].
// Exactness chain unchanged from R11: g clamped at 10 only perturbs g^2 >=
// 100 > 81; column-window min <= 81 is provably exact (excluded |i-k| >= 9
// contribute >= 81); else the EXACT brute-force fallback fires (P ~ 1e-26).
// ---------------------------------------------------------------------------
__global__ __launch_bounds__(1024) void merged_kernel(
    const int* __restrict__ tgt, const float* __restrict__ in,
    float* __restrict__ partials) {
  __shared__ u16x4 s2[32][64];    // sat g^2, row r <-> k = i0-8+r = 16 KB
  __shared__ float s_w[16];
  const int bid = blockIdx.x;     // n*64 + it*4 + jt  (8*16*4 = 512)
  const int n = bid >> 6;
  const int it = (bid >> 2) & 15;
  const int jt = bid & 3;
  const int i0 = it * 16, j0 = jt * 64;
  const int tid = threadIdx.x;
  const int lane = tid & 63;
  const int w = tid >> 6;         // wave 0..15; pixel row i = i0 + w
  const int j = j0 + lane;
  const int i = i0 + w;

  // ---- logit loads up front (consumed only in phase 6) ----
  const long cs = (long)Hh * Ww;
  const float* lp = in + ((long)(n * Cc) * Hh + i) * Ww + j;
  const float x0 = lp[0];
  const float x1 = lp[cs];
  const float x2 = lp[2 * cs];
  const float x3 = lp[3 * cs];

  // ---- tgt loads for this wave's 2 mask rows (clamped addrs, no branch) ----
  const int k0r = i0 - 8 + 2 * w;
  int t_[2][4];
#pragma unroll
  for (int rr = 0; rr < 2; ++rr) {
    const int kc = min(max(k0r + rr, 0), Hh - 1);
    const int rowOff = (n * Hh + kc) * Ww + lane;
#pragma unroll
    for (int q = 0; q < 4; ++q) t_[rr][q] = tgt[rowOff + q * 64];
  }

  // ---- wave-local mask build + funnel/clz -> clamped g^2 -> s2 ----
  const bool laneLo = (lane < 32);
  const int sh = (lane + 32) & 63;
  const u16 SENT = 0xFE00;        // 65024; +dd(<=64) < 65536, no wrap
#pragma unroll
  for (int rr = 0; rr < 2; ++rr) {
    const int r = 2 * w + rr;
    const int k = k0r + rr;
    u16x4 sq = {SENT, SENT, SENT, SENT};
    if (k >= 0 && k < Hh) {       // wave-uniform
      u16 dv[4];
#pragma unroll
      for (int c = 0; c < Cc; ++c) {
        const u64 M0 = __ballot(t_[rr][0] == c);
        const u64 M1 = __ballot(t_[rr][1] == c);
        const u64 M2 = __ballot(t_[rr][2] == c);
        const u64 M3 = __ballot(t_[rr][3] == c);
        // uniform word picks (jt is block-uniform -> scalar cselects)
        const u64 Wm1 = (jt == 0) ? 0ull
                       : ((jt == 1) ? M0 : ((jt == 2) ? M1 : M2));
        const u64 W0 = (jt == 0) ? M0
                      : ((jt == 1) ? M1 : ((jt == 2) ? M2 : M3));
        const u64 Wp1 = (jt == 3) ? 0ull
                       : ((jt == 0) ? M1 : ((jt == 1) ? M2 : M3));
        const u64 lo = laneLo ? Wm1 : W0;
        const u64 hi = laneLo ? W0 : Wp1;
        const u64 win = sh ? ((lo >> sh) | (hi << (64 - sh))) : lo;
        const u64 ml = win & 0x1FFFFFFFFull;   // bits [j-32, j]
        const u64 mr = win >> 32;              // bits [j, j+31]
        const int dl = ml ? (__builtin_clzll(ml) - 31) : 512;
        const int dr = mr ? (int)__builtin_ctzll(mr) : 512;
        const int dd = min(min(dl, dr), 10);   // clamp 10 (exactness: header)
        dv[c] = (u16)(dd * dd);
      }
      sq.x = dv[0]; sq.y = dv[1]; sq.z = dv[2]; sq.w = dv[3];
    }
    s2[r][lane] = sq;
  }
  __syncthreads();                // the ONLY barrier before the reduction

  // ---- 17-tap column window, 1 px/thread: rows w .. w+16 ----
  u16x4 acc = {0xFFFF, 0xFFFF, 0xFFFF, 0xFFFF};
#pragma unroll
  for (int kq = 0; kq <= 16; ++kq) {
    const int dd = (8 - kq) * (8 - kq);       // compile-time constant
    const u16x4 ddv = {(u16)dd, (u16)dd, (u16)dd, (u16)dd};
    const u16x4 t = s2[w + kq][lane] + ddv;   // b64 read + 2x pk_add
    acc = __builtin_elementwise_min(acc, t);  // 2x pk_min
  }
  int d0 = acc.x, d1 = acc.y, d2 = acc.z, d3 = acc.w;

  // ---- exactness check; rare EXACT brute-force fallback ----
  if (max(max(d0, d1), max(d2, d3)) > 81) {   // P ~ 1e-26, exact if taken
    d0 = 0x7fffffff; d1 = 0x7fffffff; d2 = 0x7fffffff; d3 = 0x7fffffff;
    const int* tp = tgt + n * (Hh * Ww);
    for (int p = 0; p < Hh * Ww; ++p) {
      const int t = tp[p];
      const int dy = i - (p >> 8);
      const int dx = j - (p & 255);
      const int dd2 = dy * dy + dx * dx;
      d0 = (t == 0) ? min(d0, dd2) : d0;
      d1 = (t == 1) ? min(d1, dd2) : d1;
      d2 = (t == 2) ? min(d2, dd2) : d2;
      d3 = (t == 3) ? min(d3, dd2) : d3;
    }
  }

  // ---- softmax + loss ----
  const float f0 = (float)d0, f1 = (float)d1;  // exact: < 2^24
  const float f2 = (float)d2, f3 = (float)d3;
  const float mx = fmaxf(fmaxf(x0, x1), fmaxf(x2, x3));
  const float e0 = __expf(x0 - mx), e1 = __expf(x1 - mx);
  const float e2 = __expf(x2 - mx), e3 = __expf(x3 - mx);
  const float rs = 1.0f / (e0 + e1 + e2 + e3);
  const float p0 = e0 * rs, p1 = e1 * rs, p2 = e2 * rs, p3 = e3 * rs;
  // own-class d is exactly 0; exclude it for dbar
  const int q0 = (d0 == 0) ? 0x7fffffff : d0;
  const int q1 = (d1 == 0) ? 0x7fffffff : d1;
  const int q2 = (d2 == 0) ? 0x7fffffff : d2;
  const int q3 = (d3 == 0) ? 0x7fffffff : d3;
  const float dbar = (float)min(min(q0, q1), min(q2, q3));
  const float pt = (d0 == 0) ? p0 : (d1 == 0) ? p1 : (d2 == 0) ? p2 : p3;
  float contrib = pt * sqrtf(dbar) -
                  (p0 * sqrtf(f0) + p1 * sqrtf(f1) +
                   p2 * sqrtf(f2) + p3 * sqrtf(f3));

  // ---- block reduction (deterministic fixed order) ----
#pragma unroll
  for (int off = 32; off > 0; off >>= 1) contrib += __shfl_down(contrib, off);
  if (lane == 0) s_w[w] = contrib;
  __syncthreads();
  if (tid == 0) {
    float v = 0.0f;
#pragma unroll
    for (int q = 0; q < 16; ++q) v += s_w[q];
    partials[bid] = v;            // plain store (no fence/ticket: R7 lesson)
  }
}

// ---------------------------------------------------------------------------
// Finalize: deterministic reduction of 512 partials + scaling
// ---------------------------------------------------------------------------
__global__ __launch_bounds__(256) void finalize_kernel(
    const float* __restrict__ partials, float* __restrict__ out) {
  __shared__ float s_red[256];
  const int tid = threadIdx.x;
  const float v0 = partials[tid];
  const float v1 = partials[tid + 256];
  s_red[tid] = v0 + v1;
  __syncthreads();
  for (int st = 128; st > 0; st >>= 1) {
    if (tid < st) s_red[tid] += s_red[tid + st];
    __syncthreads();
  }
  if (tid == 0)
    out[0] = s_red[0] / (float)(Cc * Nn) / (65536.0f + 1e-6f);
}

extern "C" void kernel_launch(void* const* d_in, const int* in_sizes, int n_in,
                              void* d_out, int out_size, void* d_ws, size_t ws_size,
                              hipStream_t stream) {
  const float* input = (const float*)d_in[0];   // [8,4,256,256] fp32 logits
  const int* target = (const int*)d_in[1];      // [8,256,256] int32
  float* out = (float*)d_out;                   // scalar fp32
  float* partials = (float*)((char*)d_ws + OFF_PART);

  merged_kernel<<<dim3(512), dim3(1024), 0, stream>>>(target, input, partials);
  finalize_kernel<<<dim3(1), dim3(256), 0, stream>>>(partials, out);
}

// Round 14
// 13.999 us; speedup vs baseline: 8.4116x; 1.1675x over previous
//
#include <hip/hip_runtime.h>

#define Nn 8
#define Cc 4
#define Hh 256
#define Ww 256

typedef unsigned int u32;
typedef unsigned short u16;
typedef u16 u16x4 __attribute__((ext_vector_type(4)));
typedef unsigned long long u64;

// Workspace layout (bytes): partials only
#define OFF_PART 0

// ---------------------------------------------------------------------------
// Merged kernel: block = 1024 thr (16 waves), 16i x 64j tile, 1 px/thread.
// R14 changes (w-reduction, structure identical to R13):
//  * 32-bit funnel: clamp-10 needs only bits [j-16, j+15]. Padded word space
//    V[0..9] = [0, W0..W7, 0] (W = 8 u32 words of the 256-bit row mask);
//    window starts at padded bit ps = j+16 -> lo=V[ps>>5], hi=V[ps>>5 + 1],
//    win = alignbit(hi, lo, ps&31). Bit 16 of win = column j.
//    dl = clz32(ml|1)-15 (ml = win & 0x1FFFF): if no left bit, computes 16,
//    which post-clamp-10 is identical to the true >=17. dr = ctz32(mr|2^16).
//  * symmetric-pair taps: acc = min(acc, min(s2[c-o], s2[c+o]) + o*o).
//  * __builtin_amdgcn_sqrtf / rcpf (~1 ulp) replace precise sqrt/div.
// Exactness chain unchanged: clamp only perturbs g^2 >= 100 > 81; window min
// <= 81 provably exact (excluded |dy| >= 9 contribute >= 81); else EXACT
// brute-force fallback (P ~ 1e-26 on random data).
// ---------------------------------------------------------------------------
__global__ __launch_bounds__(1024) void merged_kernel(
    const int* __restrict__ tgt, const float* __restrict__ in,
    float* __restrict__ partials) {
  __shared__ u16x4 s2[32][64];    // sat g^2, row r <-> k = i0-8+r = 16 KB
  __shared__ float s_w[16];
  const int bid = blockIdx.x;     // n*64 + it*4 + jt  (8*16*4 = 512)
  const int n = bid >> 6;
  const int it = (bid >> 2) & 15;
  const int jt = bid & 3;
  const int i0 = it * 16, j0 = jt * 64;
  const int tid = threadIdx.x;
  const int lane = tid & 63;
  const int w = tid >> 6;         // wave 0..15; pixel row i = i0 + w
  const int j = j0 + lane;
  const int i = i0 + w;

  // ---- logit loads up front (consumed only in the loss phase) ----
  const long cs = (long)Hh * Ww;
  const float* lp = in + ((long)(n * Cc) * Hh + i) * Ww + j;
  const float x0 = lp[0];
  const float x1 = lp[cs];
  const float x2 = lp[2 * cs];
  const float x3 = lp[3 * cs];

  // ---- tgt loads for this wave's 2 mask rows (clamped addrs, no branch) ----
  const int k0r = i0 - 8 + 2 * w;
  int t_[2][4];
#pragma unroll
  for (int rr = 0; rr < 2; ++rr) {
    const int kc = min(max(k0r + rr, 0), Hh - 1);
    const int rowOff = (n * Hh + kc) * Ww + lane;
#pragma unroll
    for (int q = 0; q < 4; ++q) t_[rr][q] = tgt[rowOff + q * 64];
  }

  // ---- per-thread window constants (hoisted) ----
  const int lane16 = lane + 16;
  const bool c0 = (lane16 < 32);        // sel == 0
  const bool c1 = (lane16 >= 32) && (lane16 < 64);  // sel == 1
  const u32 shift = (u32)(lane16 & 31);
  const u16 SENT = 0xFE00;              // 65024; +dd(<=64) < 65536, no wrap

  // ---- wave-local mask build + 32-bit funnel -> clamped g^2 -> s2 ----
#pragma unroll
  for (int rr = 0; rr < 2; ++rr) {
    const int r = 2 * w + rr;
    const int k = k0r + rr;
    u16x4 sq = {SENT, SENT, SENT, SENT};
    if (k >= 0 && k < Hh) {             // wave-uniform
      u16 dv[4];
#pragma unroll
      for (int c = 0; c < Cc; ++c) {
        const u64 M0 = __ballot(t_[rr][0] == c);  // cols [0,63]
        const u64 M1 = __ballot(t_[rr][1] == c);  // cols [64,127]
        const u64 M2 = __ballot(t_[rr][2] == c);  // cols [128,191]
        const u64 M3 = __ballot(t_[rr][3] == c);  // cols [192,255]
        const u32 W0 = (u32)M0, W1 = (u32)(M0 >> 32);
        const u32 W2 = (u32)M1, W3 = (u32)(M1 >> 32);
        const u32 W4 = (u32)M2, W5 = (u32)(M2 >> 32);
        const u32 W6 = (u32)M3, W7 = (u32)(M3 >> 32);
        // U_m = V[2*jt + m], V = [0, W0..W7, 0]  (jt block-uniform -> SALU)
        const u32 U0 = (jt == 0) ? 0u : ((jt == 1) ? W1 : ((jt == 2) ? W3 : W5));
        const u32 U1 = (jt == 0) ? W0 : ((jt == 1) ? W2 : ((jt == 2) ? W4 : W6));
        const u32 U2 = (jt == 0) ? W1 : ((jt == 1) ? W3 : ((jt == 2) ? W5 : W7));
        const u32 U3 = (jt == 0) ? W2 : ((jt == 1) ? W4 : ((jt == 2) ? W6 : 0u));
        const u32 lo = c0 ? U0 : (c1 ? U1 : U2);
        const u32 hi = c0 ? U1 : (c1 ? U2 : U3);
        const u32 win = __builtin_amdgcn_alignbit(hi, lo, shift);
        const u32 ml = win & 0x1FFFFu;  // columns [j-16, j] (bit 16 = col j)
        const u32 mr = win >> 16;       // columns [j, j+15]
        const int dl = __builtin_clz(ml | 1u) - 15;      // ml==0 -> 16 (safe)
        const int dr = __builtin_ctz(mr | 0x10000u);     // mr==0 -> 16 (safe)
        const int dd = min(min(dl, dr), 10);
        dv[c] = (u16)(dd * dd);
      }
      sq.x = dv[0]; sq.y = dv[1]; sq.z = dv[2]; sq.w = dv[3];
    }
    s2[r][lane] = sq;
  }
  __syncthreads();                // the ONLY barrier before the reduction

  // ---- 17-tap column window, symmetric pairs: rows w .. w+16 ----
  u16x4 acc = s2[w + 8][lane];    // o = 0: the pixel's own row (always valid)
#pragma unroll
  for (int o = 1; o <= 8; ++o) {
    const u16x4 pr =
        __builtin_elementwise_min(s2[w + 8 - o][lane], s2[w + 8 + o][lane]);
    const u16 dd = (u16)(o * o);
    const u16x4 ddv = {dd, dd, dd, dd};
    acc = __builtin_elementwise_min(acc, pr + ddv);
  }
  int d0 = acc.x, d1 = acc.y, d2 = acc.z, d3 = acc.w;

  // ---- exactness check; rare EXACT brute-force fallback ----
  if (max(max(d0, d1), max(d2, d3)) > 81) {   // P ~ 1e-26, exact if taken
    d0 = 0x7fffffff; d1 = 0x7fffffff; d2 = 0x7fffffff; d3 = 0x7fffffff;
    const int* tp = tgt + n * (Hh * Ww);
    for (int p = 0; p < Hh * Ww; ++p) {
      const int t = tp[p];
      const int dy = i - (p >> 8);
      const int dx = j - (p & 255);
      const int dd2 = dy * dy + dx * dx;
      d0 = (t == 0) ? min(d0, dd2) : d0;
      d1 = (t == 1) ? min(d1, dd2) : d1;
      d2 = (t == 2) ? min(d2, dd2) : d2;
      d3 = (t == 3) ? min(d3, dd2) : d3;
    }
  }

  // ---- softmax + loss (HW-approx sqrt/rcp: ~1 ulp vs 3.3e-3 threshold) ----
  const float f0 = (float)d0, f1 = (float)d1;  // exact: < 2^24
  const float f2 = (float)d2, f3 = (float)d3;
  const float mx = fmaxf(fmaxf(x0, x1), fmaxf(x2, x3));
  const float e0 = __expf(x0 - mx), e1 = __expf(x1 - mx);
  const float e2 = __expf(x2 - mx), e3 = __expf(x3 - mx);
  const float rs = __builtin_amdgcn_rcpf(e0 + e1 + e2 + e3);
  const float p0 = e0 * rs, p1 = e1 * rs, p2 = e2 * rs, p3 = e3 * rs;
  // own-class d is exactly 0; exclude it for dbar
  const int q0 = (d0 == 0) ? 0x7fffffff : d0;
  const int q1 = (d1 == 0) ? 0x7fffffff : d1;
  const int q2 = (d2 == 0) ? 0x7fffffff : d2;
  const int q3 = (d3 == 0) ? 0x7fffffff : d3;
  const float dbar = (float)min(min(q0, q1), min(q2, q3));
  const float pt = (d0 == 0) ? p0 : (d1 == 0) ? p1 : (d2 == 0) ? p2 : p3;
  float contrib = pt * __builtin_amdgcn_sqrtf(dbar) -
                  (p0 * __builtin_amdgcn_sqrtf(f0) +
                   p1 * __builtin_amdgcn_sqrtf(f1) +
                   p2 * __builtin_amdgcn_sqrtf(f2) +
                   p3 * __builtin_amdgcn_sqrtf(f3));

  // ---- block reduction (deterministic fixed order) ----
#pragma unroll
  for (int off = 32; off > 0; off >>= 1) contrib += __shfl_down(contrib, off);
  if (lane == 0) s_w[w] = contrib;
  __syncthreads();
  if (tid == 0) {
    float v = 0.0f;
#pragma unroll
    for (int q = 0; q < 16; ++q) v += s_w[q];
    partials[bid] = v;            // plain store (no fence/ticket: R7 lesson)
  }
}

// ---------------------------------------------------------------------------
// Finalize: deterministic reduction of 512 partials + scaling
// ---------------------------------------------------------------------------
__global__ __launch_bounds__(256) void finalize_kernel(
    const float* __restrict__ partials, float* __restrict__ out) {
  __shared__ float s_red[256];
  const int tid = threadIdx.x;
  const float v0 = partials[tid];
  const float v1 = partials[tid + 256];
  s_red[tid] = v0 + v1;
  __syncthreads();
  for (int st = 128; st > 0; st >>= 1) {
    if (tid < st) s_red[tid] += s_red[tid + st];
    __syncthreads();
  }
  if (tid == 0)
    out[0] = s_red[0] / (float)(Cc * Nn) / (65536.0f + 1e-6f);
}

extern "C" void kernel_launch(void* const* d_in, const int* in_sizes, int n_in,
                              void* d_out, int out_size, void* d_ws, size_t ws_size,
                              hipStream_t stream) {
  const float* input = (const float*)d_in[0];   // [8,4,256,256] fp32 logits
  const int* target = (const int*)d_in[1];      // [8,256,256] int32
  float* out = (float*)d_out;                   // scalar fp32
  float* partials = (float*)((char*)d_ws + OFF_PART);

  merged_kernel<<<dim3(512), dim3(1024), 0, stream>>>(target, input, partials);
  finalize_kernel<<<dim3(1), dim3(256), 0, stream>>>(partials, out);
}